// Round 17
// baseline (150.617 us; speedup 1.0000x reference)
//
#include <hip/hip_runtime.h>

// NCC2D fused: 5 box-sums (9x9, zero-pad) + cc + global mean.
// R9 (resubmitted R17 -- eight GPU timeouts, never ran): STAGE-THEN-COMPUTE.
// R7 vs R8 proved the bottleneck is the per-wave serial chain (same ~50us /
// ~28% VALUBusy with 4x different residency and free barriers), not wave
// count: 24 per-row iterations each serialized on load->ring->Vbuf->fence->
// 25 ds_reads. New structure per 64-thread block (wave == workgroup),
// 128col x 16row output tile:
//   phase 1: stage the whole 24-row x 136-col (I,J) tile into LDS -- 48
//            independent global loads, ONE latency drain, one barrier.
//   phase 2: fence-free fully-unrolled compute: per row, 5x ds_read_b128
//            window reads + ~80 VALU for all 5 horizontal 9-sums; vertical
//            sliding V = +H(new) - H(recomputed old): 39 H per block, no
//            H-ring, no Vbuf, no per-row fences; deep intra-wave ILP.
// LDS 26.1KB -> 6 blocks/CU (R7/R8 showed extra waves don't help; ILP
// replaces TLP). launch_bounds(64,1) = full VGPR budget, no heuristic spill.
// d_ws: 4096 block partials (float). Kernel 2 reduces in double -> -mean.

#define BATCH     32
#define IMH       512
#define IMW       512
#define SH        16          // output rows per block
#define NROWSTRIP 32          // 512/16
#define NCOLSTRIP 4           // 512/128
#define CBW       128         // output cols per block
#define NK        (SH + 8)    // staged input rows (24)
#define TW        136         // staged cols: 4 halo + 128 + 4 halo
#define NPART     (BATCH * NROWSTRIP * NCOLSTRIP)   // 4096

// horizontal 9-window sums for the lane's 2 output cols from staged row K.
// tile[K][l0..l0+9] = cols c0-4..c0+5; float4 read = 2 cols of (I,J).
#define HCALC(K, HI0,HI1,HJ0,HJ1,HA0,HA1,HB0,HB1,HC0,HC1) do {             \
    const float4 w0_ = *(const float4*)&tile[K][l0];                       \
    const float4 w1_ = *(const float4*)&tile[K][l0 + 2];                   \
    const float4 w2_ = *(const float4*)&tile[K][l0 + 4];                   \
    const float4 w3_ = *(const float4*)&tile[K][l0 + 6];                   \
    const float4 w4_ = *(const float4*)&tile[K][l0 + 8];                   \
    HI0 = ((w0_.x + w0_.z) + (w1_.x + w1_.z))                              \
        + ((w2_.x + w2_.z) + (w3_.x + w3_.z)) + w4_.x;                     \
    HI1 = HI0 + w4_.z - w0_.x;                                             \
    HJ0 = ((w0_.y + w0_.w) + (w1_.y + w1_.w))                              \
        + ((w2_.y + w2_.w) + (w3_.y + w3_.w)) + w4_.y;                     \
    HJ1 = HJ0 + w4_.w - w0_.y;                                             \
    HA0 = ((w0_.x*w0_.x + w0_.z*w0_.z) + (w1_.x*w1_.x + w1_.z*w1_.z))      \
        + ((w2_.x*w2_.x + w2_.z*w2_.z) + (w3_.x*w3_.x + w3_.z*w3_.z))      \
        + w4_.x*w4_.x;                                                     \
    HA1 = HA0 + w4_.z*w4_.z - w0_.x*w0_.x;                                 \
    HB0 = ((w0_.y*w0_.y + w0_.w*w0_.w) + (w1_.y*w1_.y + w1_.w*w1_.w))      \
        + ((w2_.y*w2_.y + w2_.w*w2_.w) + (w3_.y*w3_.y + w3_.w*w3_.w))      \
        + w4_.y*w4_.y;                                                     \
    HB1 = HB0 + w4_.w*w4_.w - w0_.y*w0_.y;                                 \
    HC0 = ((w0_.x*w0_.y + w0_.z*w0_.w) + (w1_.x*w1_.y + w1_.z*w1_.w))      \
        + ((w2_.x*w2_.y + w2_.z*w2_.w) + (w3_.x*w3_.y + w3_.z*w3_.w))      \
        + w4_.x*w4_.y;                                                     \
    HC1 = HC0 + w4_.z*w4_.w - w0_.x*w0_.y;                                 \
} while (0)

#define CC1(AI, AJ, S2, S3, S4) do {                                       \
    const float cross = (S4) - (AI)*(AJ)*inv81;                            \
    const float ivv   = (S2) - (AI)*(AI)*inv81;                            \
    const float jvv   = (S3) - (AJ)*(AJ)*inv81;                            \
    acc += cross * cross * __builtin_amdgcn_rcpf(ivv * jvv + 1e-5f);       \
} while (0)

__global__ __launch_bounds__(64, 1) void ncc_main(const float* __restrict__ I,
                                                  const float* __restrict__ J,
                                                  float* __restrict__ partial) {
    const int u    = threadIdx.x;        // 0..63
    const int cs   = blockIdx.x;         // col strip (0..3)
    const int s    = blockIdx.y;         // row strip (0..31)
    const int b    = blockIdx.z;         // image
    const int r0   = s * SH;
    const int cblk = cs * CBW;
    const int stc  = cblk - 4 + 2 * u;   // lane's 2 staged cols (abs, even)
    const int hc   = cblk + 124 + u;     // right-halo col for lanes 0..7
    const int l0   = 2 * u;              // tile idx of col c0-4
    const float inv81 = 1.0f / 81.0f;

    const float* Ib = I + (size_t)b * IMH * IMW;
    const float* Jb = J + (size_t)b * IMH * IMW;

    __shared__ float2 tile[NK][TW];      // 26.1 KB: (I,J) per col

    // ---- phase 1: stage 24 rows x 136 cols; all loads independent ----
#pragma unroll
    for (int k = 0; k < NK; ++k) {
        const int ri = r0 - 4 + k;
        float2 iv = make_float2(0.f, 0.f), jv = make_float2(0.f, 0.f);
        float hi = 0.f, hj = 0.f;
        if ((unsigned)ri < (unsigned)IMH) {
            const float* rI = Ib + (size_t)ri * IMW;
            const float* rJ = Jb + (size_t)ri * IMW;
            if ((unsigned)stc < (unsigned)IMW) {   // pair never straddles edge
                iv = *(const float2*)(rI + stc);
                jv = *(const float2*)(rJ + stc);
            }
            if (u < 8 && (unsigned)hc < (unsigned)IMW) {
                hi = rI[hc]; hj = rJ[hc];
            }
        }
        // interleaved (I,J): cols stc, stc+1 -> tile idx 2u, 2u+1 (one b128)
        *(float4*)&tile[k][2 * u] = make_float4(iv.x, jv.x, iv.y, jv.y);
        if (u < 8) tile[k][128 + u] = make_float2(hi, hj);
    }
    __syncthreads();   // single-wave workgroup: cheap

    // ---- phase 2: fence-free compute, fully unrolled ----
    float vI0 = 0.f, vI1 = 0.f, vJ0 = 0.f, vJ1 = 0.f;
    float vA0 = 0.f, vA1 = 0.f, vB0 = 0.f, vB1 = 0.f;
    float vC0 = 0.f, vC1 = 0.f;
    float acc = 0.f;

    {   // V = sum of H(0..8); emit output row r0
        float hI0, hI1, hJ0, hJ1, hA0, hA1, hB0, hB1, hC0, hC1;
#pragma unroll
        for (int k = 0; k < 9; ++k) {
            HCALC(k, hI0, hI1, hJ0, hJ1, hA0, hA1, hB0, hB1, hC0, hC1);
            vI0 += hI0; vI1 += hI1; vJ0 += hJ0; vJ1 += hJ1;
            vA0 += hA0; vA1 += hA1; vB0 += hB0; vB1 += hB1;
            vC0 += hC0; vC1 += hC1;
        }
        CC1(vI0, vJ0, vA0, vB0, vC0);
        CC1(vI1, vJ1, vA1, vB1, vC1);
    }

#pragma unroll
    for (int t = 1; t < SH; ++t) {   // slide: +H(t+8) - H(t-1) (recomputed)
        float nI0, nI1, nJ0, nJ1, nA0, nA1, nB0, nB1, nC0, nC1;
        float oI0, oI1, oJ0, oJ1, oA0, oA1, oB0, oB1, oC0, oC1;
        HCALC(t + 8, nI0, nI1, nJ0, nJ1, nA0, nA1, nB0, nB1, nC0, nC1);
        HCALC(t - 1, oI0, oI1, oJ0, oJ1, oA0, oA1, oB0, oB1, oC0, oC1);
        vI0 += nI0 - oI0; vI1 += nI1 - oI1;
        vJ0 += nJ0 - oJ0; vJ1 += nJ1 - oJ1;
        vA0 += nA0 - oA0; vA1 += nA1 - oA1;
        vB0 += nB0 - oB0; vB1 += nB1 - oB1;
        vC0 += nC0 - oC0; vC1 += nC1 - oC1;
        CC1(vI0, vJ0, vA0, vB0, vC0);
        CC1(vI1, vJ1, vA1, vB1, vC1);
    }

    // single-wave reduction; lane 0 writes the block partial
    float sum = acc;
#pragma unroll
    for (int off = 32; off > 0; off >>= 1) sum += __shfl_down(sum, off, 64);
    if (u == 0) {
        partial[((size_t)b * NROWSTRIP + s) * NCOLSTRIP + cs] = sum;
    }
}

__global__ __launch_bounds__(256) void ncc_reduce(const float* __restrict__ partial,
                                                  float* __restrict__ out) {
    const int t = threadIdx.x;
    double ssum = 0.0;
    for (int idx = t; idx < NPART; idx += 256) ssum += (double)partial[idx];
#pragma unroll
    for (int off = 32; off > 0; off >>= 1) ssum += __shfl_down(ssum, off, 64);

    __shared__ double wsum[4];
    if ((t & 63) == 0) wsum[t >> 6] = ssum;
    __syncthreads();
    if (t == 0) {
        const double total = wsum[0] + wsum[1] + wsum[2] + wsum[3];
        out[0] = (float)(-total / 8388608.0);  // -mean over 32*512*512
    }
}

extern "C" void kernel_launch(void* const* d_in, const int* in_sizes, int n_in,
                              void* d_out, int out_size, void* d_ws, size_t ws_size,
                              hipStream_t stream) {
    const float* I = (const float*)d_in[0];  // y_true
    const float* J = (const float*)d_in[1];  // y_pred
    float* partial = (float*)d_ws;           // NPART floats
    float* out     = (float*)d_out;

    dim3 grid(NCOLSTRIP, NROWSTRIP, BATCH);
    ncc_main<<<grid, 64, 0, stream>>>(I, J, partial);
    ncc_reduce<<<1, 256, 0, stream>>>(partial, out);
}